// Round 11
// baseline (760.299 us; speedup 1.0000x reference)
//
#include <hip/hip_runtime.h>
#include <hip/hip_bf16.h>
#include <math.h>

#define LN_EPS 1e-5f

constexpr int Bb = 8, Ss = 2048, Ee = 512, Ll = 6, Ff = 2048, Cc = 10;
constexpr int Nn = Bb * Ss;  // 16384 rows

typedef __attribute__((ext_vector_type(8))) short short8v;
typedef __attribute__((ext_vector_type(4))) float f32x4;

__device__ __forceinline__ unsigned short f2bf(float f) {
    unsigned int b = __float_as_uint(f);
    b += 0x7FFFu + ((b >> 16) & 1u);   // RNE
    return (unsigned short)(b >> 16);
}

__device__ __forceinline__ float fastcos(float x) {
    float r = x * 0.15915494309189535f;     // radians -> revolutions
    r = __builtin_amdgcn_fractf(r);         // reduce to [0,1)
    return __builtin_amdgcn_cosf(r);        // v_cos_f32
}

// async global->LDS, 16B per lane. LDS dest = wave-uniform base + lane*16.
__device__ __forceinline__ void gload16(const void* g, void* lds) {
    __builtin_amdgcn_global_load_lds(
        (__attribute__((address_space(1))) void*)(g),
        (__attribute__((address_space(3))) void*)(lds),
        16, 0, 0);
}

// ---------------- positional encoding table ----------------
__global__ void pe_kernel(float* __restrict__ pe) {
    int p = blockIdx.x * blockDim.x + threadIdx.x;
    int total = Ss * (Ee / 2);
    if (p >= total) return;
    int s = p / (Ee / 2);
    int i = p % (Ee / 2);
    float div = expf(float(2 * i) * (-logf(10000.0f) / float(Ee)));
    float ang = float(s) * div;
    pe[s * Ee + 2 * i]     = sinf(ang);
    pe[s * Ee + 2 * i + 1] = cosf(ang);
}

// ---------------- embedding + PE (+ Acos for layer 0) ----------------
__global__ void embed_kernel(const int* __restrict__ tokens,
                             const float* __restrict__ emb,
                             const float* __restrict__ pe,
                             const float* __restrict__ theta0,
                             float* __restrict__ x,
                             unsigned short* __restrict__ acos) {
    int idx = blockIdx.x * blockDim.x + threadIdx.x;
    int total = Nn * Ee / 4;
    if (idx >= total) return;
    int n  = idx / (Ee / 4);
    int e4 = idx % (Ee / 4);
    int tok = tokens[n];
    int s = n % Ss;
    f32x4 a = *(const f32x4*)(emb + (size_t)tok * Ee + e4 * 4);
    f32x4 p = *(const f32x4*)(pe + (size_t)s * Ee + e4 * 4);
    f32x4 o = a + p;
    *(f32x4*)(x + (size_t)n * Ee + e4 * 4) = o;
    f32x4 t = *(const f32x4*)(theta0 + e4 * 4);
    ushort4 c;
    c.x = f2bf(fastcos(o.x + t.x));
    c.y = f2bf(fastcos(o.y + t.y));
    c.z = f2bf(fastcos(o.z + t.z));
    c.w = f2bf(fastcos(o.w + t.w));
    *(ushort4*)(acos + (size_t)n * Ee + e4 * 4) = c;
}

// ---------------- fp32 -> bf16 weight conversion ----------------
__global__ void cvt_bf16(const float* __restrict__ in,
                         unsigned short* __restrict__ out, int n4) {
    int i = blockIdx.x * blockDim.x + threadIdx.x;
    if (i >= n4) return;
    f32x4 v = *(const f32x4*)(in + (size_t)i * 4);
    ushort4 o;
    o.x = f2bf(v.x); o.y = f2bf(v.y); o.z = f2bf(v.z); o.w = f2bf(v.w);
    *(ushort4*)(out + (size_t)i * 4) = o;
}

// ---------------- H = bf16(relu(z @ W1^T + b1)) ----------------
// Block = 8 z-rows x 2048 f. Thread t handles f = t + 256*j: coalesced W1
// loads; h staged in LDS then b128 coalesced stores.
__global__ __launch_bounds__(256) void h_kernel(const float* __restrict__ z,
                                                const float* __restrict__ W1,
                                                const float* __restrict__ b1,
                                                unsigned short* __restrict__ H) {
    __shared__ unsigned short hls[8 * Ff];
    const int t  = threadIdx.x;
    const int m0 = blockIdx.x * 8;
    f32x4 zr[8];
#pragma unroll
    for (int r = 0; r < 8; ++r)
        zr[r] = *(const f32x4*)(z + (size_t)(m0 + r) * 4);
#pragma unroll
    for (int j = 0; j < 8; ++j) {
        const int f = t + 256 * j;
        f32x4 w = *(const f32x4*)(W1 + (size_t)f * 4);  // coalesced
        float bb = b1[f];                               // coalesced
#pragma unroll
        for (int r = 0; r < 8; ++r) {
            float v = zr[r].x * w.x + zr[r].y * w.y + zr[r].z * w.z +
                      zr[r].w * w.w + bb;
            hls[r * Ff + f] = f2bf(fmaxf(v, 0.f));
        }
    }
    __syncthreads();
#pragma unroll
    for (int j = 0; j < 8; ++j) {
        const int idx = (j * 256 + t) * 8;   // ushort index, 16B per thread
        *(short8v*)(H + (size_t)m0 * Ff + idx) = *(const short8v*)(&hls[idx]);
    }
}

// =========== bf16 GEMM: Cout = A @ Wb^T + bias + xres ===========
// A: M x K bf16, Wb: 512 x K bf16, Cout/xres: M x 512 fp32.
// Tile 64x128, BK=64, 4 waves (2x2, each 32x64), 16x16x32 bf16 MFMA.
// Grid = (M/64)*(N/128) = 1024 blocks -> 4 blocks/CU (round-10 lesson:
// 512-block grid capped occupancy at 2 blocks/CU = 25%). Double-buffered
// LDS (48 KB -> 3 blocks/CU) + counted vmcnt(6): next tile's loads stay
// in flight across the barrier (round-8 structure, beat single-buf).
// Staging: global_load_lds x16B, pre-swizzled SOURCE (chunk ^= row&7),
// linear LDS dest; reads apply the same XOR (proven 0 bank conflicts).
// XCD-chunked swizzle (1024 = 8 x 128), col-fast: the 4 col-blocks of
// one A row-tile share an XCD's L2.
__global__ __launch_bounds__(256) void gemm_bf16(
    const unsigned short* __restrict__ A,
    const unsigned short* __restrict__ Wb,
    const float* __restrict__ bias,
    const float* __restrict__ xres,
    float* __restrict__ Cout,
    int K) {
    __shared__ unsigned short As[2][64 * 64];
    __shared__ unsigned short Bs[2][128 * 64];
    const int tid  = threadIdx.x;
    const int lane = tid & 63;
    const int wid  = tid >> 6;     // 0..3
    const int wr   = wid >> 1;     // 0..1 (32-row band)
    const int wc   = wid & 1;      // 0..1 (64-col band)
    // XCD-chunked swizzle: 1024 wgs = 8 xcds x 128; col-fast within chunk.
    const int wg   = blockIdx.x;
    const int sw   = (wg & 7) * 128 + (wg >> 3);
    const int row0 = (sw >> 2) * 64;
    const int col0 = (sw & 3) * 128;
    const int srow   = lane >> 3;  // 0..7 row within 8-row segment
    const int pchunk = lane & 7;   // physical chunk this lane's 16B lands in

    f32x4 acc[2][4];
#pragma unroll
    for (int m = 0; m < 2; m++)
#pragma unroll
        for (int n = 0; n < 4; n++) acc[m][n] = {0.f, 0.f, 0.f, 0.f};

    const int NT = K >> 6;

    auto STAGE = [&](int buf, int k0) {
#pragma unroll
        for (int i = 0; i < 2; ++i) {           // A: 8 segments of 8 rows
            const int s   = wid * 2 + i;
            const int row = s * 8 + srow;       // 0..63
            const int lc  = pchunk ^ (row & 7);
            gload16(A + (size_t)(row0 + row) * K + k0 + lc * 8, &As[buf][s * 512]);
        }
#pragma unroll
        for (int i = 0; i < 4; ++i) {           // B: 16 segments of 8 rows
            const int s   = wid * 4 + i;
            const int row = s * 8 + srow;       // 0..127
            const int lc  = pchunk ^ (row & 7);
            gload16(Wb + (size_t)(col0 + row) * K + k0 + lc * 8, &Bs[buf][s * 512]);
        }
    };

    auto COMPUTE = [&](int buf) {
#pragma unroll
        for (int ks = 0; ks < 2; ks++) {
            const int k8 = ks * 4 + (lane >> 4);
            short8v aF[2], bF[4];
#pragma unroll
            for (int m = 0; m < 2; m++) {
                const int row = wr * 32 + m * 16 + (lane & 15);
                aF[m] = *(const short8v*)(&As[buf][row * 64 + ((k8 ^ (row & 7)) * 8)]);
            }
#pragma unroll
            for (int n = 0; n < 4; n++) {
                const int row = wc * 64 + n * 16 + (lane & 15);
                bF[n] = *(const short8v*)(&Bs[buf][row * 64 + ((k8 ^ (row & 7)) * 8)]);
            }
#pragma unroll
            for (int m = 0; m < 2; m++)
#pragma unroll
                for (int n = 0; n < 4; n++)
                    acc[m][n] = __builtin_amdgcn_mfma_f32_16x16x32_bf16(
                        aF[m], bF[n], acc[m][n], 0, 0, 0);
        }
    };

    STAGE(0, 0);
    int cur = 0;
    for (int kt = 0; kt < NT; ++kt) {
        if (kt + 1 < NT) {
            STAGE(cur ^ 1, (kt + 1) << 6);             // issue next-tile loads
            asm volatile("s_waitcnt vmcnt(6)" ::: "memory");  // cur's 6 landed
        } else {
            asm volatile("s_waitcnt vmcnt(0)" ::: "memory");
        }
        __builtin_amdgcn_s_barrier();                  // all waves' cur-stage visible
        asm volatile("" ::: "memory");
        COMPUTE(cur);
        asm volatile("" ::: "memory");
        __builtin_amdgcn_s_barrier();                  // reads of cur done before restage
        cur ^= 1;
    }

#pragma unroll
    for (int m = 0; m < 2; m++) {
#pragma unroll
        for (int n = 0; n < 4; n++) {
            int colg = col0 + wc * 64 + n * 16 + (lane & 15);
            float bv = bias[colg];
#pragma unroll
            for (int j = 0; j < 4; j++) {
                int rowg = row0 + wr * 32 + m * 16 + ((lane >> 4) * 4) + j;
                size_t off = (size_t)rowg * 512 + colg;
                Cout[off] = acc[m][n][j] + bv + xres[off];
            }
        }
    }
}

// ---------------- LN (wave per row); optional z / Acos fusion ------
__global__ __launch_bounds__(256) void ln_fused(
    const float* __restrict__ tmp, float* __restrict__ x,
    const float* __restrict__ g, const float* __restrict__ b,
    const float* __restrict__ phi, float* __restrict__ z,
    const float* __restrict__ theta, unsigned short* __restrict__ acos) {
    const int row  = blockIdx.x * 4 + (threadIdx.x >> 6);
    const int lane = threadIdx.x & 63;
    const float* tr = tmp + (size_t)row * Ee;
    f32x4 v0 = *(const f32x4*)(tr + lane * 4);
    f32x4 v1 = *(const f32x4*)(tr + 256 + lane * 4);
    float s = v0.x + v0.y + v0.z + v0.w + v1.x + v1.y + v1.z + v1.w;
#pragma unroll
    for (int o = 32; o; o >>= 1) s += __shfl_xor(s, o);
    float mu = s * (1.f / 512.f);
    f32x4 d0 = {v0.x - mu, v0.y - mu, v0.z - mu, v0.w - mu};
    f32x4 d1 = {v1.x - mu, v1.y - mu, v1.z - mu, v1.w - mu};
    float q = d0.x * d0.x + d0.y * d0.y + d0.z * d0.z + d0.w * d0.w +
              d1.x * d1.x + d1.y * d1.y + d1.z * d1.z + d1.w * d1.w;
#pragma unroll
    for (int o = 32; o; o >>= 1) q += __shfl_xor(q, o);
    float rs = rsqrtf(q * (1.f / 512.f) + LN_EPS);
    f32x4 g0 = *(const f32x4*)(g + lane * 4);
    f32x4 b0 = *(const f32x4*)(b + lane * 4);
    f32x4 g1 = *(const f32x4*)(g + 256 + lane * 4);
    f32x4 b1v = *(const f32x4*)(b + 256 + lane * 4);
    f32x4 o0 = {d0.x * rs * g0.x + b0.x, d0.y * rs * g0.y + b0.y,
                d0.z * rs * g0.z + b0.z, d0.w * rs * g0.w + b0.w};
    f32x4 o1 = {d1.x * rs * g1.x + b1v.x, d1.y * rs * g1.y + b1v.y,
                d1.z * rs * g1.z + b1v.z, d1.w * rs * g1.w + b1v.w};
    *(f32x4*)(x + (size_t)row * Ee + lane * 4) = o0;
    *(f32x4*)(x + (size_t)row * Ee + 256 + lane * 4) = o1;
    if (z != nullptr && lane == 0) {
        z[(size_t)row * 4 + 0] = fastcos(o0.x) * fastcos(phi[0]);
        z[(size_t)row * 4 + 1] = fastcos(o0.y) * fastcos(phi[1]);
        z[(size_t)row * 4 + 2] = fastcos(o0.z) * fastcos(phi[2]);
        z[(size_t)row * 4 + 3] = fastcos(o0.w) * fastcos(phi[3]);
    }
    if (acos != nullptr) {
        f32x4 t0 = *(const f32x4*)(theta + lane * 4);
        f32x4 t1 = *(const f32x4*)(theta + 256 + lane * 4);
        ushort4 c0, c1;
        c0.x = f2bf(fastcos(o0.x + t0.x));
        c0.y = f2bf(fastcos(o0.y + t0.y));
        c0.z = f2bf(fastcos(o0.z + t0.z));
        c0.w = f2bf(fastcos(o0.w + t0.w));
        c1.x = f2bf(fastcos(o1.x + t1.x));
        c1.y = f2bf(fastcos(o1.y + t1.y));
        c1.z = f2bf(fastcos(o1.z + t1.z));
        c1.w = f2bf(fastcos(o1.w + t1.w));
        *(ushort4*)(acos + (size_t)row * Ee + lane * 4) = c0;
        *(ushort4*)(acos + (size_t)row * Ee + 256 + lane * 4) = c1;
    }
}

// ---------------- parallel pool: partial sums over 64-row chunks --------
__global__ __launch_bounds__(256) void pool_part(const float* __restrict__ x,
                                                 float* __restrict__ part) {
    int bidx = blockIdx.x, ch = blockIdx.y;
    int t = threadIdx.x;
    float s0 = 0.f, s1 = 0.f;
    for (int s = 0; s < 64; ++s) {
        const float* row = x + ((size_t)bidx * Ss + ch * 64 + s) * Ee;
        s0 += row[t];
        s1 += row[t + 256];
    }
    float* pr = part + ((size_t)(bidx * 32 + ch)) * Ee;
    pr[t] = s0;
    pr[t + 256] = s1;
}

// ---------------- finish pool + classifier ----------------
__global__ __launch_bounds__(256) void cls_kernel(const float* __restrict__ part,
                                                  const float* __restrict__ clsW,
                                                  const float* __restrict__ clsb,
                                                  float* __restrict__ out) {
    int bidx = blockIdx.x;
    int t = threadIdx.x;
    float p0 = 0.f, p1 = 0.f;
    for (int ch = 0; ch < 32; ++ch) {
        const float* pr = part + ((size_t)(bidx * 32 + ch)) * Ee;
        p0 += pr[t];
        p1 += pr[t + 256];
    }
    p0 *= (1.f / float(Ss));
    p1 *= (1.f / float(Ss));
    __shared__ float red[256];
    for (int c = 0; c < Cc; ++c) {
        red[t] = p0 * clsW[(size_t)c * Ee + t] + p1 * clsW[(size_t)c * Ee + t + 256];
        __syncthreads();
        for (int s2 = 128; s2 > 0; s2 >>= 1) {
            if (t < s2) red[t] += red[t + s2];
            __syncthreads();
        }
        if (t == 0) out[bidx * Cc + c] = red[0] + clsb[c];
        __syncthreads();
    }
}

extern "C" void kernel_launch(void* const* d_in, const int* in_sizes, int n_in,
                              void* d_out, int out_size, void* d_ws, size_t ws_size,
                              hipStream_t stream) {
    const int*   tokens     = (const int*)d_in[0];
    const float* emb        = (const float*)d_in[1];
    const float* theta_attn = (const float*)d_in[2];
    const float* combine_W  = (const float*)d_in[3];
    const float* combine_b  = (const float*)d_in[4];
    const float* ln1_g      = (const float*)d_in[5];
    const float* ln1_b      = (const float*)d_in[6];
    const float* phi_ffn    = (const float*)d_in[7];
    const float* lin1_W     = (const float*)d_in[8];
    const float* lin1_b     = (const float*)d_in[9];
    const float* lin2_W     = (const float*)d_in[10];
    const float* lin2_b     = (const float*)d_in[11];
    const float* ln2_g      = (const float*)d_in[12];
    const float* ln2_b      = (const float*)d_in[13];
    const float* cls_W      = (const float*)d_in[14];
    const float* cls_b      = (const float*)d_in[15];
    float* out = (float*)d_out;

    float* x    = (float*)d_ws;                 // 16384*512 f32   (32MB)
    float* tmp  = x + (size_t)Nn * Ee;          // 32MB
    float* z    = tmp + (size_t)Nn * Ee;        // 256KB
    float* part = z + (size_t)Nn * 4;           // 512KB
    unsigned short* Wcb  = (unsigned short*)(part + (size_t)Bb * 32 * Ee); // 3MB
    unsigned short* W2b  = Wcb + (size_t)Ll * Ee * Ee;                     // 12MB
    unsigned short* acos = W2b + (size_t)Ll * Ee * Ff;                     // 16MB
    unsigned short* H    = acos + (size_t)Nn * Ee;                         // 64MB
    float* pe = (float*)H;  // overlay: pe (4MB) only used before first h_kernel

    {
        int total = Ss * (Ee / 2);
        pe_kernel<<<(total + 255) / 256, 256, 0, stream>>>(pe);
    }
    {
        int total = Nn * Ee / 4;
        embed_kernel<<<(total + 255) / 256, 256, 0, stream>>>(
            tokens, emb, pe, theta_attn, x, acos);
    }
    {
        int n4c = Ll * Ee * Ee / 4;
        cvt_bf16<<<(n4c + 255) / 256, 256, 0, stream>>>(combine_W, Wcb, n4c);
        int n42 = Ll * Ee * Ff / 4;
        cvt_bf16<<<(n42 + 255) / 256, 256, 0, stream>>>(lin2_W, W2b, n42);
    }

    const int ngemm = (Nn / 64) * (Ee / 128);  // 1024 blocks, 1D + swizzle
    for (int l = 0; l < Ll; l++) {
        const unsigned short* cWl = Wcb + (size_t)l * Ee * Ee;
        const float* cbl  = combine_b + (size_t)l * Ee;
        const float* g1   = ln1_g + (size_t)l * Ee;
        const float* b1n  = ln1_b + (size_t)l * Ee;
        const float* phil = phi_ffn + (size_t)l * 4;
        const float* w1l  = lin1_W + (size_t)l * Ff * 4;
        const float* b1l  = lin1_b + (size_t)l * Ff;
        const unsigned short* w2l = W2b + (size_t)l * Ee * Ff;
        const float* b2l  = lin2_b + (size_t)l * Ee;
        const float* g2   = ln2_g + (size_t)l * Ee;
        const float* b2n  = ln2_b + (size_t)l * Ee;
        const float* thn  = (l + 1 < Ll) ? theta_attn + (size_t)(l + 1) * Ee : nullptr;
        unsigned short* acn = (l + 1 < Ll) ? acos : nullptr;

        // tmp = x + Acos @ Wc^T + cb
        gemm_bf16<<<ngemm, 256, 0, stream>>>(acos, cWl, cbl, x, tmp, Ee);
        // x = LN(tmp); z = cos(x[:,:4])*cos(phi)
        ln_fused<<<Nn / 4, 256, 0, stream>>>(tmp, x, g1, b1n, phil, z,
                                             nullptr, nullptr);
        // H = bf16(relu(z @ W1^T + b1))
        h_kernel<<<Nn / 8, 256, 0, stream>>>(z, w1l, b1l, H);
        // tmp = x + H @ W2^T + b2
        gemm_bf16<<<ngemm, 256, 0, stream>>>(H, w2l, b2l, x, tmp, Ff);
        // x = LN(tmp); Acos = bf16(cos(x + theta_{l+1}))  (except last layer)
        ln_fused<<<Nn / 4, 256, 0, stream>>>(tmp, x, g2, b2n, nullptr, nullptr,
                                             thn, acn);
    }

    pool_part<<<dim3(Bb, 32), 256, 0, stream>>>(x, part);
    cls_kernel<<<Bb, 256, 0, stream>>>(part, cls_W, cls_b, out);
}

// Round 12
// 660.878 us; speedup vs baseline: 1.1504x; 1.1504x over previous
//
#include <hip/hip_runtime.h>
#include <hip/hip_bf16.h>
#include <math.h>

#define LN_EPS 1e-5f

constexpr int Bb = 8, Ss = 2048, Ee = 512, Ll = 6, Ff = 2048, Cc = 10;
constexpr int Nn = Bb * Ss;  // 16384 rows

typedef __attribute__((ext_vector_type(8))) short short8v;
typedef __attribute__((ext_vector_type(4))) float f32x4;

__device__ __forceinline__ unsigned short f2bf(float f) {
    unsigned int b = __float_as_uint(f);
    b += 0x7FFFu + ((b >> 16) & 1u);   // RNE
    return (unsigned short)(b >> 16);
}

__device__ __forceinline__ float fastcos(float x) {
    float r = x * 0.15915494309189535f;     // radians -> revolutions
    r = __builtin_amdgcn_fractf(r);         // reduce to [0,1)
    return __builtin_amdgcn_cosf(r);        // v_cos_f32
}

// async global->LDS, 16B per lane. LDS dest = wave-uniform base + lane*16.
__device__ __forceinline__ void gload16(const void* g, void* lds) {
    __builtin_amdgcn_global_load_lds(
        (__attribute__((address_space(1))) void*)(g),
        (__attribute__((address_space(3))) void*)(lds),
        16, 0, 0);
}

// ---------------- positional encoding table ----------------
__global__ void pe_kernel(float* __restrict__ pe) {
    int p = blockIdx.x * blockDim.x + threadIdx.x;
    int total = Ss * (Ee / 2);
    if (p >= total) return;
    int s = p / (Ee / 2);
    int i = p % (Ee / 2);
    float div = expf(float(2 * i) * (-logf(10000.0f) / float(Ee)));
    float ang = float(s) * div;
    pe[s * Ee + 2 * i]     = sinf(ang);
    pe[s * Ee + 2 * i + 1] = cosf(ang);
}

// ---------------- embedding + PE (+ Acos for layer 0) ----------------
__global__ void embed_kernel(const int* __restrict__ tokens,
                             const float* __restrict__ emb,
                             const float* __restrict__ pe,
                             const float* __restrict__ theta0,
                             float* __restrict__ x,
                             unsigned short* __restrict__ acos) {
    int idx = blockIdx.x * blockDim.x + threadIdx.x;
    int total = Nn * Ee / 4;
    if (idx >= total) return;
    int n  = idx / (Ee / 4);
    int e4 = idx % (Ee / 4);
    int tok = tokens[n];
    int s = n % Ss;
    f32x4 a = *(const f32x4*)(emb + (size_t)tok * Ee + e4 * 4);
    f32x4 p = *(const f32x4*)(pe + (size_t)s * Ee + e4 * 4);
    f32x4 o = a + p;
    *(f32x4*)(x + (size_t)n * Ee + e4 * 4) = o;
    f32x4 t = *(const f32x4*)(theta0 + e4 * 4);
    ushort4 c;
    c.x = f2bf(fastcos(o.x + t.x));
    c.y = f2bf(fastcos(o.y + t.y));
    c.z = f2bf(fastcos(o.z + t.z));
    c.w = f2bf(fastcos(o.w + t.w));
    *(ushort4*)(acos + (size_t)n * Ee + e4 * 4) = c;
}

// ---------------- fp32 -> bf16 weight conversion ----------------
__global__ void cvt_bf16(const float* __restrict__ in,
                         unsigned short* __restrict__ out, int n4) {
    int i = blockIdx.x * blockDim.x + threadIdx.x;
    if (i >= n4) return;
    f32x4 v = *(const f32x4*)(in + (size_t)i * 4);
    ushort4 o;
    o.x = f2bf(v.x); o.y = f2bf(v.y); o.z = f2bf(v.z); o.w = f2bf(v.w);
    *(ushort4*)(out + (size_t)i * 4) = o;
}

// ---------------- H = bf16(relu(z @ W1^T + b1)) ----------------
// Block = 8 z-rows x 2048 f. Thread t handles f = t + 256*j: coalesced W1
// loads; h staged in LDS then b128 coalesced stores.
__global__ __launch_bounds__(256) void h_kernel(const float* __restrict__ z,
                                                const float* __restrict__ W1,
                                                const float* __restrict__ b1,
                                                unsigned short* __restrict__ H) {
    __shared__ unsigned short hls[8 * Ff];
    const int t  = threadIdx.x;
    const int m0 = blockIdx.x * 8;
    f32x4 zr[8];
#pragma unroll
    for (int r = 0; r < 8; ++r)
        zr[r] = *(const f32x4*)(z + (size_t)(m0 + r) * 4);
#pragma unroll
    for (int j = 0; j < 8; ++j) {
        const int f = t + 256 * j;
        f32x4 w = *(const f32x4*)(W1 + (size_t)f * 4);  // coalesced
        float bb = b1[f];                               // coalesced
#pragma unroll
        for (int r = 0; r < 8; ++r) {
            float v = zr[r].x * w.x + zr[r].y * w.y + zr[r].z * w.z +
                      zr[r].w * w.w + bb;
            hls[r * Ff + f] = f2bf(fmaxf(v, 0.f));
        }
    }
    __syncthreads();
#pragma unroll
    for (int j = 0; j < 8; ++j) {
        const int idx = (j * 256 + t) * 8;   // ushort index, 16B per thread
        *(short8v*)(H + (size_t)m0 * Ff + idx) = *(const short8v*)(&hls[idx]);
    }
}

// =========== bf16 GEMM: Cout = A @ Wb^T + bias + xres ===========
// A: M x K bf16, Wb: 512 x K bf16, Cout/xres: M x 512 fp32.
// Tile 128x128, BK=64, EIGHT waves (2x4; each wave 64 rows x 32 cols,
// acc[4][2]), 16x16x32 bf16 MFMA. Round-8 dbuf structure (best measured:
// 50.4us) but 512-thread blocks: grid 512 = 2 blocks/CU x 8 waves
// = 16 waves/CU (50% ceiling) vs round-8's 8 waves/CU (25%) -- the
// occupancy was wave-count-capped, not LDS-capped (rounds 10/11).
// ~80 VGPR < 128 so 4 waves/SIMD allowed; LDS 2x64KB = 128KB/CU fits.
// Staging: global_load_lds x16B, pre-swizzled SOURCE (chunk ^= row&7),
// linear LDS dest; reads apply the same XOR (0 bank conflicts measured).
// Counted vmcnt(4): next tile's 4 loads stay in flight across barrier.
// XCD-chunked swizzle (512 = 8 x 64), col-fast.
__global__ __launch_bounds__(512, 4) void gemm_bf16(
    const unsigned short* __restrict__ A,
    const unsigned short* __restrict__ Wb,
    const float* __restrict__ bias,
    const float* __restrict__ xres,
    float* __restrict__ Cout,
    int K) {
    __shared__ unsigned short As[2][128 * 64];
    __shared__ unsigned short Bs[2][128 * 64];
    const int tid  = threadIdx.x;
    const int lane = tid & 63;
    const int wid  = tid >> 6;     // 0..7
    const int wr   = wid >> 2;     // 0..1 (64-row band)
    const int wc   = wid & 3;      // 0..3 (32-col band)
    // XCD-chunked swizzle: 512 wgs = 8 xcds x 64; col-fast within chunk.
    const int wg   = blockIdx.x;
    const int sw   = (wg & 7) * 64 + (wg >> 3);
    const int row0 = (sw >> 2) * 128;
    const int col0 = (sw & 3) * 128;
    const int srow   = lane >> 3;  // 0..7 row within 8-row segment
    const int pchunk = lane & 7;   // physical chunk this lane's 16B lands in

    f32x4 acc[4][2];
#pragma unroll
    for (int m = 0; m < 4; m++)
#pragma unroll
        for (int n = 0; n < 2; n++) acc[m][n] = {0.f, 0.f, 0.f, 0.f};

    const int NT = K >> 6;

    auto STAGE = [&](int buf, int k0) {
#pragma unroll
        for (int i = 0; i < 2; ++i) {           // A: 16 segments of 8 rows
            const int s   = wid * 2 + i;        // 0..15
            const int row = s * 8 + srow;       // 0..127
            const int lc  = pchunk ^ (row & 7); // inverse-swizzled source chunk
            gload16(A  + (size_t)(row0 + row) * K + k0 + lc * 8, &As[buf][s * 512]);
        }
#pragma unroll
        for (int i = 0; i < 2; ++i) {           // B: 16 segments of 8 rows
            const int s   = wid * 2 + i;
            const int row = s * 8 + srow;
            const int lc  = pchunk ^ (row & 7);
            gload16(Wb + (size_t)(col0 + row) * K + k0 + lc * 8, &Bs[buf][s * 512]);
        }
    };

    auto COMPUTE = [&](int buf) {
#pragma unroll
        for (int ks = 0; ks < 2; ks++) {
            const int k8 = ks * 4 + (lane >> 4);
            short8v aF[4], bF[2];
#pragma unroll
            for (int m = 0; m < 4; m++) {
                const int row = wr * 64 + m * 16 + (lane & 15);
                aF[m] = *(const short8v*)(&As[buf][row * 64 + ((k8 ^ (row & 7)) * 8)]);
            }
#pragma unroll
            for (int n = 0; n < 2; n++) {
                const int row = wc * 32 + n * 16 + (lane & 15);
                bF[n] = *(const short8v*)(&Bs[buf][row * 64 + ((k8 ^ (row & 7)) * 8)]);
            }
#pragma unroll
            for (int m = 0; m < 4; m++)
#pragma unroll
                for (int n = 0; n < 2; n++)
                    acc[m][n] = __builtin_amdgcn_mfma_f32_16x16x32_bf16(
                        aF[m], bF[n], acc[m][n], 0, 0, 0);
        }
    };

    STAGE(0, 0);
    int cur = 0;
    for (int kt = 0; kt < NT; ++kt) {
        if (kt + 1 < NT) {
            STAGE(cur ^ 1, (kt + 1) << 6);             // issue next-tile loads
            asm volatile("s_waitcnt vmcnt(4)" ::: "memory");  // cur's 4 landed
        } else {
            asm volatile("s_waitcnt vmcnt(0)" ::: "memory");
        }
        __builtin_amdgcn_s_barrier();                  // all waves' cur-stage visible
        asm volatile("" ::: "memory");
        COMPUTE(cur);
        asm volatile("" ::: "memory");
        __builtin_amdgcn_s_barrier();                  // reads of cur done before restage
        cur ^= 1;
    }

#pragma unroll
    for (int m = 0; m < 4; m++) {
#pragma unroll
        for (int n = 0; n < 2; n++) {
            int colg = col0 + wc * 32 + n * 16 + (lane & 15);
            float bv = bias[colg];
#pragma unroll
            for (int j = 0; j < 4; j++) {
                int rowg = row0 + wr * 64 + m * 16 + ((lane >> 4) * 4) + j;
                size_t off = (size_t)rowg * 512 + colg;
                Cout[off] = acc[m][n][j] + bv + xres[off];
            }
        }
    }
}

// ---------------- LN (wave per row); optional z / Acos fusion ------
__global__ __launch_bounds__(256) void ln_fused(
    const float* __restrict__ tmp, float* __restrict__ x,
    const float* __restrict__ g, const float* __restrict__ b,
    const float* __restrict__ phi, float* __restrict__ z,
    const float* __restrict__ theta, unsigned short* __restrict__ acos) {
    const int row  = blockIdx.x * 4 + (threadIdx.x >> 6);
    const int lane = threadIdx.x & 63;
    const float* tr = tmp + (size_t)row * Ee;
    f32x4 v0 = *(const f32x4*)(tr + lane * 4);
    f32x4 v1 = *(const f32x4*)(tr + 256 + lane * 4);
    float s = v0.x + v0.y + v0.z + v0.w + v1.x + v1.y + v1.z + v1.w;
#pragma unroll
    for (int o = 32; o; o >>= 1) s += __shfl_xor(s, o);
    float mu = s * (1.f / 512.f);
    f32x4 d0 = {v0.x - mu, v0.y - mu, v0.z - mu, v0.w - mu};
    f32x4 d1 = {v1.x - mu, v1.y - mu, v1.z - mu, v1.w - mu};
    float q = d0.x * d0.x + d0.y * d0.y + d0.z * d0.z + d0.w * d0.w +
              d1.x * d1.x + d1.y * d1.y + d1.z * d1.z + d1.w * d1.w;
#pragma unroll
    for (int o = 32; o; o >>= 1) q += __shfl_xor(q, o);
    float rs = rsqrtf(q * (1.f / 512.f) + LN_EPS);
    f32x4 g0 = *(const f32x4*)(g + lane * 4);
    f32x4 b0 = *(const f32x4*)(b + lane * 4);
    f32x4 g1 = *(const f32x4*)(g + 256 + lane * 4);
    f32x4 b1v = *(const f32x4*)(b + 256 + lane * 4);
    f32x4 o0 = {d0.x * rs * g0.x + b0.x, d0.y * rs * g0.y + b0.y,
                d0.z * rs * g0.z + b0.z, d0.w * rs * g0.w + b0.w};
    f32x4 o1 = {d1.x * rs * g1.x + b1v.x, d1.y * rs * g1.y + b1v.y,
                d1.z * rs * g1.z + b1v.z, d1.w * rs * g1.w + b1v.w};
    *(f32x4*)(x + (size_t)row * Ee + lane * 4) = o0;
    *(f32x4*)(x + (size_t)row * Ee + 256 + lane * 4) = o1;
    if (z != nullptr && lane == 0) {
        z[(size_t)row * 4 + 0] = fastcos(o0.x) * fastcos(phi[0]);
        z[(size_t)row * 4 + 1] = fastcos(o0.y) * fastcos(phi[1]);
        z[(size_t)row * 4 + 2] = fastcos(o0.z) * fastcos(phi[2]);
        z[(size_t)row * 4 + 3] = fastcos(o0.w) * fastcos(phi[3]);
    }
    if (acos != nullptr) {
        f32x4 t0 = *(const f32x4*)(theta + lane * 4);
        f32x4 t1 = *(const f32x4*)(theta + 256 + lane * 4);
        ushort4 c0, c1;
        c0.x = f2bf(fastcos(o0.x + t0.x));
        c0.y = f2bf(fastcos(o0.y + t0.y));
        c0.z = f2bf(fastcos(o0.z + t0.z));
        c0.w = f2bf(fastcos(o0.w + t0.w));
        c1.x = f2bf(fastcos(o1.x + t1.x));
        c1.y = f2bf(fastcos(o1.y + t1.y));
        c1.z = f2bf(fastcos(o1.z + t1.z));
        c1.w = f2bf(fastcos(o1.w + t1.w));
        *(ushort4*)(acos + (size_t)row * Ee + lane * 4) = c0;
        *(ushort4*)(acos + (size_t)row * Ee + 256 + lane * 4) = c1;
    }
}

// ---------------- parallel pool: partial sums over 64-row chunks --------
__global__ __launch_bounds__(256) void pool_part(const float* __restrict__ x,
                                                 float* __restrict__ part) {
    int bidx = blockIdx.x, ch = blockIdx.y;
    int t = threadIdx.x;
    float s0 = 0.f, s1 = 0.f;
    for (int s = 0; s < 64; ++s) {
        const float* row = x + ((size_t)bidx * Ss + ch * 64 + s) * Ee;
        s0 += row[t];
        s1 += row[t + 256];
    }
    float* pr = part + ((size_t)(bidx * 32 + ch)) * Ee;
    pr[t] = s0;
    pr[t + 256] = s1;
}

// ---------------- finish pool + classifier ----------------
__global__ __launch_bounds__(256) void cls_kernel(const float* __restrict__ part,
                                                  const float* __restrict__ clsW,
                                                  const float* __restrict__ clsb,
                                                  float* __restrict__ out) {
    int bidx = blockIdx.x;
    int t = threadIdx.x;
    float p0 = 0.f, p1 = 0.f;
    for (int ch = 0; ch < 32; ++ch) {
        const float* pr = part + ((size_t)(bidx * 32 + ch)) * Ee;
        p0 += pr[t];
        p1 += pr[t + 256];
    }
    p0 *= (1.f / float(Ss));
    p1 *= (1.f / float(Ss));
    __shared__ float red[256];
    for (int c = 0; c < Cc; ++c) {
        red[t] = p0 * clsW[(size_t)c * Ee + t] + p1 * clsW[(size_t)c * Ee + t + 256];
        __syncthreads();
        for (int s2 = 128; s2 > 0; s2 >>= 1) {
            if (t < s2) red[t] += red[t + s2];
            __syncthreads();
        }
        if (t == 0) out[bidx * Cc + c] = red[0] + clsb[c];
        __syncthreads();
    }
}

extern "C" void kernel_launch(void* const* d_in, const int* in_sizes, int n_in,
                              void* d_out, int out_size, void* d_ws, size_t ws_size,
                              hipStream_t stream) {
    const int*   tokens     = (const int*)d_in[0];
    const float* emb        = (const float*)d_in[1];
    const float* theta_attn = (const float*)d_in[2];
    const float* combine_W  = (const float*)d_in[3];
    const float* combine_b  = (const float*)d_in[4];
    const float* ln1_g      = (const float*)d_in[5];
    const float* ln1_b      = (const float*)d_in[6];
    const float* phi_ffn    = (const float*)d_in[7];
    const float* lin1_W     = (const float*)d_in[8];
    const float* lin1_b     = (const float*)d_in[9];
    const float* lin2_W     = (const float*)d_in[10];
    const float* lin2_b     = (const float*)d_in[11];
    const float* ln2_g      = (const float*)d_in[12];
    const float* ln2_b      = (const float*)d_in[13];
    const float* cls_W      = (const float*)d_in[14];
    const float* cls_b      = (const float*)d_in[15];
    float* out = (float*)d_out;

    float* x    = (float*)d_ws;                 // 16384*512 f32   (32MB)
    float* tmp  = x + (size_t)Nn * Ee;          // 32MB
    float* z    = tmp + (size_t)Nn * Ee;        // 256KB
    float* part = z + (size_t)Nn * 4;           // 512KB
    unsigned short* Wcb  = (unsigned short*)(part + (size_t)Bb * 32 * Ee); // 3MB
    unsigned short* W2b  = Wcb + (size_t)Ll * Ee * Ee;                     // 12MB
    unsigned short* acos = W2b + (size_t)Ll * Ee * Ff;                     // 16MB
    unsigned short* H    = acos + (size_t)Nn * Ee;                         // 64MB
    float* pe = (float*)H;  // overlay: pe (4MB) only used before first h_kernel

    {
        int total = Ss * (Ee / 2);
        pe_kernel<<<(total + 255) / 256, 256, 0, stream>>>(pe);
    }
    {
        int total = Nn * Ee / 4;
        embed_kernel<<<(total + 255) / 256, 256, 0, stream>>>(
            tokens, emb, pe, theta_attn, x, acos);
    }
    {
        int n4c = Ll * Ee * Ee / 4;
        cvt_bf16<<<(n4c + 255) / 256, 256, 0, stream>>>(combine_W, Wcb, n4c);
        int n42 = Ll * Ee * Ff / 4;
        cvt_bf16<<<(n42 + 255) / 256, 256, 0, stream>>>(lin2_W, W2b, n42);
    }

    const int ngemm = (Nn / 128) * (Ee / 128);  // 512 blocks, 1D + swizzle
    for (int l = 0; l < Ll; l++) {
        const unsigned short* cWl = Wcb + (size_t)l * Ee * Ee;
        const float* cbl  = combine_b + (size_t)l * Ee;
        const float* g1   = ln1_g + (size_t)l * Ee;
        const float* b1n  = ln1_b + (size_t)l * Ee;
        const float* phil = phi_ffn + (size_t)l * 4;
        const float* w1l  = lin1_W + (size_t)l * Ff * 4;
        const float* b1l  = lin1_b + (size_t)l * Ff;
        const unsigned short* w2l = W2b + (size_t)l * Ee * Ff;
        const float* b2l  = lin2_b + (size_t)l * Ee;
        const float* g2   = ln2_g + (size_t)l * Ee;
        const float* b2n  = ln2_b + (size_t)l * Ee;
        const float* thn  = (l + 1 < Ll) ? theta_attn + (size_t)(l + 1) * Ee : nullptr;
        unsigned short* acn = (l + 1 < Ll) ? acos : nullptr;

        // tmp = x + Acos @ Wc^T + cb
        gemm_bf16<<<ngemm, 512, 0, stream>>>(acos, cWl, cbl, x, tmp, Ee);
        // x = LN(tmp); z = cos(x[:,:4])*cos(phi)
        ln_fused<<<Nn / 4, 256, 0, stream>>>(tmp, x, g1, b1n, phil, z,
                                             nullptr, nullptr);
        // H = bf16(relu(z @ W1^T + b1))
        h_kernel<<<Nn / 8, 256, 0, stream>>>(z, w1l, b1l, H);
        // tmp = x + H @ W2^T + b2
        gemm_bf16<<<ngemm, 512, 0, stream>>>(H, w2l, b2l, x, tmp, Ff);
        // x = LN(tmp); Acos = bf16(cos(x + theta_{l+1}))  (except last layer)
        ln_fused<<<Nn / 4, 256, 0, stream>>>(tmp, x, g2, b2n, nullptr, nullptr,
                                             thn, acn);
    }

    pool_part<<<dim3(Bb, 32), 256, 0, stream>>>(x, part);
    cls_kernel<<<Bb, 256, 0, stream>>>(part, cls_W, cls_b, out);
}

// Round 13
// 638.768 us; speedup vs baseline: 1.1903x; 1.0346x over previous
//
#include <hip/hip_runtime.h>
#include <hip/hip_bf16.h>
#include <math.h>

#define LN_EPS 1e-5f

constexpr int Bb = 8, Ss = 2048, Ee = 512, Ll = 6, Ff = 2048, Cc = 10;
constexpr int Nn = Bb * Ss;  // 16384 rows

typedef __attribute__((ext_vector_type(8))) short short8v;
typedef __attribute__((ext_vector_type(4))) float f32x4;

__device__ __forceinline__ unsigned short f2bf(float f) {
    unsigned int b = __float_as_uint(f);
    b += 0x7FFFu + ((b >> 16) & 1u);   // RNE
    return (unsigned short)(b >> 16);
}

__device__ __forceinline__ float fastcos(float x) {
    float r = x * 0.15915494309189535f;     // radians -> revolutions
    r = __builtin_amdgcn_fractf(r);         // reduce to [0,1)
    return __builtin_amdgcn_cosf(r);        // v_cos_f32
}

// async global->LDS, 16B per lane. LDS dest = wave-uniform base + lane*16.
__device__ __forceinline__ void gload16(const void* g, void* lds) {
    __builtin_amdgcn_global_load_lds(
        (__attribute__((address_space(1))) void*)(g),
        (__attribute__((address_space(3))) void*)(lds),
        16, 0, 0);
}

// ---------------- positional encoding table ----------------
__global__ void pe_kernel(float* __restrict__ pe) {
    int p = blockIdx.x * blockDim.x + threadIdx.x;
    int total = Ss * (Ee / 2);
    if (p >= total) return;
    int s = p / (Ee / 2);
    int i = p % (Ee / 2);
    float div = expf(float(2 * i) * (-logf(10000.0f) / float(Ee)));
    float ang = float(s) * div;
    pe[s * Ee + 2 * i]     = sinf(ang);
    pe[s * Ee + 2 * i + 1] = cosf(ang);
}

// ---------------- embedding + PE (+ Acos for layer 0) ----------------
__global__ void embed_kernel(const int* __restrict__ tokens,
                             const float* __restrict__ emb,
                             const float* __restrict__ pe,
                             const float* __restrict__ theta0,
                             float* __restrict__ x,
                             unsigned short* __restrict__ acos) {
    int idx = blockIdx.x * blockDim.x + threadIdx.x;
    int total = Nn * Ee / 4;
    if (idx >= total) return;
    int n  = idx / (Ee / 4);
    int e4 = idx % (Ee / 4);
    int tok = tokens[n];
    int s = n % Ss;
    f32x4 a = *(const f32x4*)(emb + (size_t)tok * Ee + e4 * 4);
    f32x4 p = *(const f32x4*)(pe + (size_t)s * Ee + e4 * 4);
    f32x4 o = a + p;
    *(f32x4*)(x + (size_t)n * Ee + e4 * 4) = o;
    f32x4 t = *(const f32x4*)(theta0 + e4 * 4);
    ushort4 c;
    c.x = f2bf(fastcos(o.x + t.x));
    c.y = f2bf(fastcos(o.y + t.y));
    c.z = f2bf(fastcos(o.z + t.z));
    c.w = f2bf(fastcos(o.w + t.w));
    *(ushort4*)(acos + (size_t)n * Ee + e4 * 4) = c;
}

// ---------------- fp32 -> bf16 weight conversion ----------------
__global__ void cvt_bf16(const float* __restrict__ in,
                         unsigned short* __restrict__ out, int n4) {
    int i = blockIdx.x * blockDim.x + threadIdx.x;
    if (i >= n4) return;
    f32x4 v = *(const f32x4*)(in + (size_t)i * 4);
    ushort4 o;
    o.x = f2bf(v.x); o.y = f2bf(v.y); o.z = f2bf(v.z); o.w = f2bf(v.w);
    *(ushort4*)(out + (size_t)i * 4) = o;
}

// ---------------- H = bf16(relu(z @ W1^T + b1)) ----------------
// Block = 8 z-rows x 2048 f. Thread t handles f = t + 256*j: coalesced W1
// loads; h staged in LDS then b128 coalesced stores.
__global__ __launch_bounds__(256) void h_kernel(const float* __restrict__ z,
                                                const float* __restrict__ W1,
                                                const float* __restrict__ b1,
                                                unsigned short* __restrict__ H) {
    __shared__ unsigned short hls[8 * Ff];
    const int t  = threadIdx.x;
    const int m0 = blockIdx.x * 8;
    f32x4 zr[8];
#pragma unroll
    for (int r = 0; r < 8; ++r)
        zr[r] = *(const f32x4*)(z + (size_t)(m0 + r) * 4);
#pragma unroll
    for (int j = 0; j < 8; ++j) {
        const int f = t + 256 * j;
        f32x4 w = *(const f32x4*)(W1 + (size_t)f * 4);  // coalesced
        float bb = b1[f];                               // coalesced
#pragma unroll
        for (int r = 0; r < 8; ++r) {
            float v = zr[r].x * w.x + zr[r].y * w.y + zr[r].z * w.z +
                      zr[r].w * w.w + bb;
            hls[r * Ff + f] = f2bf(fmaxf(v, 0.f));
        }
    }
    __syncthreads();
#pragma unroll
    for (int j = 0; j < 8; ++j) {
        const int idx = (j * 256 + t) * 8;   // ushort index, 16B per thread
        *(short8v*)(H + (size_t)m0 * Ff + idx) = *(const short8v*)(&hls[idx]);
    }
}

// =========== bf16 GEMM: Cout = A @ Wb^T + bias + xres ===========
// A: M x K bf16, Wb: 512 x K bf16, Cout/xres: M x 512 fp32.
// Tile 128x128, BK=64, 8 waves (2x4; wave = 64 rows x 32 cols, acc[4][2]).
// DEPTH-2 prefetch with 2 buffers (round-12 was depth-1, vmcnt wait ate
// ~50% on HBM-cold loads): hoist all ds_reads of tile kt into regs,
// lgkmcnt(0)+barrier (all waves done reading buf b), then STAGE tile kt+2
// INTO buf b while the 16 MFMAs run on registers. Loads get ~2 iters
// (~1000 cyc) to land, covering ~900 cyc HBM-miss latency; MFMA also
// overlaps the stage issue. VGPR ~100 < 128 -> 4 waves/SIMD.
// Staging: global_load_lds x16B, pre-swizzled SOURCE (chunk ^= row&7),
// linear LDS dest; reads apply the same XOR (0 bank conflicts measured).
// XCD-chunked swizzle (512 = 8 x 64), col-fast.
__global__ __launch_bounds__(512, 4) void gemm_bf16(
    const unsigned short* __restrict__ A,
    const unsigned short* __restrict__ Wb,
    const float* __restrict__ bias,
    const float* __restrict__ xres,
    float* __restrict__ Cout,
    int K) {
    __shared__ unsigned short As[2][128 * 64];
    __shared__ unsigned short Bs[2][128 * 64];
    const int tid  = threadIdx.x;
    const int lane = tid & 63;
    const int wid  = tid >> 6;     // 0..7
    const int wr   = wid >> 2;     // 0..1 (64-row band)
    const int wc   = wid & 3;      // 0..3 (32-col band)
    // XCD-chunked swizzle: 512 wgs = 8 xcds x 64; col-fast within chunk.
    const int wg   = blockIdx.x;
    const int sw   = (wg & 7) * 64 + (wg >> 3);
    const int row0 = (sw >> 2) * 128;
    const int col0 = (sw & 3) * 128;
    const int srow   = lane >> 3;  // 0..7 row within 8-row segment
    const int pchunk = lane & 7;   // physical chunk this lane's 16B lands in

    f32x4 acc[4][2];
#pragma unroll
    for (int m = 0; m < 4; m++)
#pragma unroll
        for (int n = 0; n < 2; n++) acc[m][n] = {0.f, 0.f, 0.f, 0.f};

    const int NT = K >> 6;

    auto STAGE = [&](int buf, int k0) {
#pragma unroll
        for (int i = 0; i < 2; ++i) {           // A: 16 segments of 8 rows
            const int s   = wid * 2 + i;        // 0..15
            const int row = s * 8 + srow;       // 0..127
            const int lc  = pchunk ^ (row & 7); // inverse-swizzled source chunk
            gload16(A  + (size_t)(row0 + row) * K + k0 + lc * 8, &As[buf][s * 512]);
        }
#pragma unroll
        for (int i = 0; i < 2; ++i) {           // B: 16 segments of 8 rows
            const int s   = wid * 2 + i;
            const int row = s * 8 + srow;
            const int lc  = pchunk ^ (row & 7);
            gload16(Wb + (size_t)(col0 + row) * K + k0 + lc * 8, &Bs[buf][s * 512]);
        }
    };

    STAGE(0, 0);
    if (NT > 1) STAGE(1, 64);
    for (int kt = 0; kt < NT; ++kt) {
        const int b = kt & 1;
        if (kt + 1 < NT) {
            asm volatile("s_waitcnt vmcnt(4)" ::: "memory");  // tile kt's 4 landed
        } else {
            asm volatile("s_waitcnt vmcnt(0)" ::: "memory");
        }
        __builtin_amdgcn_s_barrier();      // buf b staged by all waves
        asm volatile("" ::: "memory");
        // hoist ALL fragment reads of buf b into registers
        short8v aF[2][4], bF[2][2];
#pragma unroll
        for (int ks = 0; ks < 2; ks++) {
            const int k8 = ks * 4 + (lane >> 4);
#pragma unroll
            for (int m = 0; m < 4; m++) {
                const int row = wr * 64 + m * 16 + (lane & 15);
                aF[ks][m] = *(const short8v*)(&As[b][row * 64 + ((k8 ^ (row & 7)) * 8)]);
            }
#pragma unroll
            for (int n = 0; n < 2; n++) {
                const int row = wc * 32 + n * 16 + (lane & 15);
                bF[ks][n] = *(const short8v*)(&Bs[b][row * 64 + ((k8 ^ (row & 7)) * 8)]);
            }
        }
        asm volatile("s_waitcnt lgkmcnt(0)" ::: "memory");
        __builtin_amdgcn_s_barrier();      // all waves done reading buf b
        asm volatile("" ::: "memory");
        if (kt + 2 < NT) STAGE(b, (kt + 2) << 6);  // overwrite b; overlaps MFMA
#pragma unroll
        for (int ks = 0; ks < 2; ks++)
#pragma unroll
            for (int m = 0; m < 4; m++)
#pragma unroll
                for (int n = 0; n < 2; n++)
                    acc[m][n] = __builtin_amdgcn_mfma_f32_16x16x32_bf16(
                        aF[ks][m], bF[ks][n], acc[m][n], 0, 0, 0);
    }

#pragma unroll
    for (int m = 0; m < 4; m++) {
#pragma unroll
        for (int n = 0; n < 2; n++) {
            int colg = col0 + wc * 32 + n * 16 + (lane & 15);
            float bv = bias[colg];
#pragma unroll
            for (int j = 0; j < 4; j++) {
                int rowg = row0 + wr * 64 + m * 16 + ((lane >> 4) * 4) + j;
                size_t off = (size_t)rowg * 512 + colg;
                Cout[off] = acc[m][n][j] + bv + xres[off];
            }
        }
    }
}

// ---------------- LN (wave per row); optional z / Acos fusion ------
__global__ __launch_bounds__(256) void ln_fused(
    const float* __restrict__ tmp, float* __restrict__ x,
    const float* __restrict__ g, const float* __restrict__ b,
    const float* __restrict__ phi, float* __restrict__ z,
    const float* __restrict__ theta, unsigned short* __restrict__ acos) {
    const int row  = blockIdx.x * 4 + (threadIdx.x >> 6);
    const int lane = threadIdx.x & 63;
    const float* tr = tmp + (size_t)row * Ee;
    f32x4 v0 = *(const f32x4*)(tr + lane * 4);
    f32x4 v1 = *(const f32x4*)(tr + 256 + lane * 4);
    float s = v0.x + v0.y + v0.z + v0.w + v1.x + v1.y + v1.z + v1.w;
#pragma unroll
    for (int o = 32; o; o >>= 1) s += __shfl_xor(s, o);
    float mu = s * (1.f / 512.f);
    f32x4 d0 = {v0.x - mu, v0.y - mu, v0.z - mu, v0.w - mu};
    f32x4 d1 = {v1.x - mu, v1.y - mu, v1.z - mu, v1.w - mu};
    float q = d0.x * d0.x + d0.y * d0.y + d0.z * d0.z + d0.w * d0.w +
              d1.x * d1.x + d1.y * d1.y + d1.z * d1.z + d1.w * d1.w;
#pragma unroll
    for (int o = 32; o; o >>= 1) q += __shfl_xor(q, o);
    float rs = rsqrtf(q * (1.f / 512.f) + LN_EPS);
    f32x4 g0 = *(const f32x4*)(g + lane * 4);
    f32x4 b0 = *(const f32x4*)(b + lane * 4);
    f32x4 g1 = *(const f32x4*)(g + 256 + lane * 4);
    f32x4 b1v = *(const f32x4*)(b + 256 + lane * 4);
    f32x4 o0 = {d0.x * rs * g0.x + b0.x, d0.y * rs * g0.y + b0.y,
                d0.z * rs * g0.z + b0.z, d0.w * rs * g0.w + b0.w};
    f32x4 o1 = {d1.x * rs * g1.x + b1v.x, d1.y * rs * g1.y + b1v.y,
                d1.z * rs * g1.z + b1v.z, d1.w * rs * g1.w + b1v.w};
    *(f32x4*)(x + (size_t)row * Ee + lane * 4) = o0;
    *(f32x4*)(x + (size_t)row * Ee + 256 + lane * 4) = o1;
    if (z != nullptr && lane == 0) {
        z[(size_t)row * 4 + 0] = fastcos(o0.x) * fastcos(phi[0]);
        z[(size_t)row * 4 + 1] = fastcos(o0.y) * fastcos(phi[1]);
        z[(size_t)row * 4 + 2] = fastcos(o0.z) * fastcos(phi[2]);
        z[(size_t)row * 4 + 3] = fastcos(o0.w) * fastcos(phi[3]);
    }
    if (acos != nullptr) {
        f32x4 t0 = *(const f32x4*)(theta + lane * 4);
        f32x4 t1 = *(const f32x4*)(theta + 256 + lane * 4);
        ushort4 c0, c1;
        c0.x = f2bf(fastcos(o0.x + t0.x));
        c0.y = f2bf(fastcos(o0.y + t0.y));
        c0.z = f2bf(fastcos(o0.z + t0.z));
        c0.w = f2bf(fastcos(o0.w + t0.w));
        c1.x = f2bf(fastcos(o1.x + t1.x));
        c1.y = f2bf(fastcos(o1.y + t1.y));
        c1.z = f2bf(fastcos(o1.z + t1.z));
        c1.w = f2bf(fastcos(o1.w + t1.w));
        *(ushort4*)(acos + (size_t)row * Ee + lane * 4) = c0;
        *(ushort4*)(acos + (size_t)row * Ee + 256 + lane * 4) = c1;
    }
}

// ---------------- parallel pool: partial sums over 64-row chunks --------
__global__ __launch_bounds__(256) void pool_part(const float* __restrict__ x,
                                                 float* __restrict__ part) {
    int bidx = blockIdx.x, ch = blockIdx.y;
    int t = threadIdx.x;
    float s0 = 0.f, s1 = 0.f;
    for (int s = 0; s < 64; ++s) {
        const float* row = x + ((size_t)bidx * Ss + ch * 64 + s) * Ee;
        s0 += row[t];
        s1 += row[t + 256];
    }
    float* pr = part + ((size_t)(bidx * 32 + ch)) * Ee;
    pr[t] = s0;
    pr[t + 256] = s1;
}

// ---------------- finish pool + classifier ----------------
__global__ __launch_bounds__(256) void cls_kernel(const float* __restrict__ part,
                                                  const float* __restrict__ clsW,
                                                  const float* __restrict__ clsb,
                                                  float* __restrict__ out) {
    int bidx = blockIdx.x;
    int t = threadIdx.x;
    float p0 = 0.f, p1 = 0.f;
    for (int ch = 0; ch < 32; ++ch) {
        const float* pr = part + ((size_t)(bidx * 32 + ch)) * Ee;
        p0 += pr[t];
        p1 += pr[t + 256];
    }
    p0 *= (1.f / float(Ss));
    p1 *= (1.f / float(Ss));
    __shared__ float red[256];
    for (int c = 0; c < Cc; ++c) {
        red[t] = p0 * clsW[(size_t)c * Ee + t] + p1 * clsW[(size_t)c * Ee + t + 256];
        __syncthreads();
        for (int s2 = 128; s2 > 0; s2 >>= 1) {
            if (t < s2) red[t] += red[t + s2];
            __syncthreads();
        }
        if (t == 0) out[bidx * Cc + c] = red[0] + clsb[c];
        __syncthreads();
    }
}

extern "C" void kernel_launch(void* const* d_in, const int* in_sizes, int n_in,
                              void* d_out, int out_size, void* d_ws, size_t ws_size,
                              hipStream_t stream) {
    const int*   tokens     = (const int*)d_in[0];
    const float* emb        = (const float*)d_in[1];
    const float* theta_attn = (const float*)d_in[2];
    const float* combine_W  = (const float*)d_in[3];
    const float* combine_b  = (const float*)d_in[4];
    const float* ln1_g      = (const float*)d_in[5];
    const float* ln1_b      = (const float*)d_in[6];
    const float* phi_ffn    = (const float*)d_in[7];
    const float* lin1_W     = (const float*)d_in[8];
    const float* lin1_b     = (const float*)d_in[9];
    const float* lin2_W     = (const float*)d_in[10];
    const float* lin2_b     = (const float*)d_in[11];
    const float* ln2_g      = (const float*)d_in[12];
    const float* ln2_b      = (const float*)d_in[13];
    const float* cls_W      = (const float*)d_in[14];
    const float* cls_b      = (const float*)d_in[15];
    float* out = (float*)d_out;

    float* x    = (float*)d_ws;                 // 16384*512 f32   (32MB)
    float* tmp  = x + (size_t)Nn * Ee;          // 32MB
    float* z    = tmp + (size_t)Nn * Ee;        // 256KB
    float* part = z + (size_t)Nn * 4;           // 512KB
    unsigned short* Wcb  = (unsigned short*)(part + (size_t)Bb * 32 * Ee); // 3MB
    unsigned short* W2b  = Wcb + (size_t)Ll * Ee * Ee;                     // 12MB
    unsigned short* acos = W2b + (size_t)Ll * Ee * Ff;                     // 16MB
    unsigned short* H    = acos + (size_t)Nn * Ee;                         // 64MB
    float* pe = (float*)H;  // overlay: pe (4MB) only used before first h_kernel

    {
        int total = Ss * (Ee / 2);
        pe_kernel<<<(total + 255) / 256, 256, 0, stream>>>(pe);
    }
    {
        int total = Nn * Ee / 4;
        embed_kernel<<<(total + 255) / 256, 256, 0, stream>>>(
            tokens, emb, pe, theta_attn, x, acos);
    }
    {
        int n4c = Ll * Ee * Ee / 4;
        cvt_bf16<<<(n4c + 255) / 256, 256, 0, stream>>>(combine_W, Wcb, n4c);
        int n42 = Ll * Ee * Ff / 4;
        cvt_bf16<<<(n42 + 255) / 256, 256, 0, stream>>>(lin2_W, W2b, n42);
    }

    const int ngemm = (Nn / 128) * (Ee / 128);  // 512 blocks, 1D + swizzle
    for (int l = 0; l < Ll; l++) {
        const unsigned short* cWl = Wcb + (size_t)l * Ee * Ee;
        const float* cbl  = combine_b + (size_t)l * Ee;
        const float* g1   = ln1_g + (size_t)l * Ee;
        const float* b1n  = ln1_b + (size_t)l * Ee;
        const float* phil = phi_ffn + (size_t)l * 4;
        const float* w1l  = lin1_W + (size_t)l * Ff * 4;
        const float* b1l  = lin1_b + (size_t)l * Ff;
        const unsigned short* w2l = W2b + (size_t)l * Ee * Ff;
        const float* b2l  = lin2_b + (size_t)l * Ee;
        const float* g2   = ln2_g + (size_t)l * Ee;
        const float* b2n  = ln2_b + (size_t)l * Ee;
        const float* thn  = (l + 1 < Ll) ? theta_attn + (size_t)(l + 1) * Ee : nullptr;
        unsigned short* acn = (l + 1 < Ll) ? acos : nullptr;

        // tmp = x + Acos @ Wc^T + cb
        gemm_bf16<<<ngemm, 512, 0, stream>>>(acos, cWl, cbl, x, tmp, Ee);
        // x = LN(tmp); z = cos(x[:,:4])*cos(phi)
        ln_fused<<<Nn / 4, 256, 0, stream>>>(tmp, x, g1, b1n, phil, z,
                                             nullptr, nullptr);
        // H = bf16(relu(z @ W1^T + b1))
        h_kernel<<<Nn / 8, 256, 0, stream>>>(z, w1l, b1l, H);
        // tmp = x + H @ W2^T + b2
        gemm_bf16<<<ngemm, 512, 0, stream>>>(H, w2l, b2l, x, tmp, Ff);
        // x = LN(tmp); Acos = bf16(cos(x + theta_{l+1}))  (except last layer)
        ln_fused<<<Nn / 4, 256, 0, stream>>>(tmp, x, g2, b2n, nullptr, nullptr,
                                             thn, acn);
    }

    pool_part<<<dim3(Bb, 32), 256, 0, stream>>>(x, part);
    cls_kernel<<<Bb, 256, 0, stream>>>(part, cls_W, cls_b, out);
}